// Round 1
// baseline (1363.799 us; speedup 1.0000x reference)
//
#include <hip/hip_runtime.h>
#include <math.h>

#define U_N 6000
#define I_N 3072
#define B_N 3000

__device__ __forceinline__ float wsum64(float v) {
#pragma unroll
  for (int d = 1; d < 64; d <<= 1) v += __shfl_xor(v, d, 64);
  return v;
}

// C[M x 64] (+)= A[M x K] @ X[K x 64]
// EPI 0: atomicAdd into pre-zeroed C (split-K); 1: direct store; 2: store relu(acc + bias[col])
template <int EPI>
__global__ __launch_bounds__(256) void gemm64(
    const float* __restrict__ A, const float* __restrict__ X,
    float* __restrict__ C, const float* __restrict__ bias,
    int M, int K, int kchunk)
{
  __shared__ float As[64][68];   // padded: row stride 68 floats (272B, 16B-aligned)
  __shared__ float Xs[64][64];
  const int tid = threadIdx.x;
  const int tx = tid & 15;       // 4-col group
  const int ty = tid >> 4;       // 4-row group
  const int row0 = blockIdx.x * 64;
  const int ks = blockIdx.y * kchunk;
  if (ks >= K) return;
  const int ke = min(K, ks + kchunk);

  float acc[4][4] = {};

  for (int k0 = ks; k0 < ke; k0 += 64) {
    // ---- stage A tile (rows row0..+63, cols k0..+63), coalesced float4 ----
    {
      const int cg = tid & 15;       // col granule
      const int rr = tid >> 4;       // base row 0..15
#pragma unroll
      for (int rb = 0; rb < 4; ++rb) {
        int r = rr + rb * 16;
        int gr = row0 + r;
        int gk = k0 + cg * 4;
        float4 val = make_float4(0.f, 0.f, 0.f, 0.f);
        if (gr < M) {
          if (gk + 3 < ke) {
            val = *reinterpret_cast<const float4*>(&A[(size_t)gr * K + gk]);
          } else {
            float t[4] = {0.f, 0.f, 0.f, 0.f};
#pragma unroll
            for (int j = 0; j < 4; ++j)
              if (gk + j < ke) t[j] = A[(size_t)gr * K + gk + j];
            val = make_float4(t[0], t[1], t[2], t[3]);
          }
        }
        *reinterpret_cast<float4*>(&As[r][cg * 4]) = val;
      }
      // ---- stage X tile (rows k0..+63, 64 cols) ----
#pragma unroll
      for (int kb = 0; kb < 4; ++kb) {
        int kr = rr + kb * 16;
        float4 val = make_float4(0.f, 0.f, 0.f, 0.f);
        if (k0 + kr < ke)
          val = *reinterpret_cast<const float4*>(&X[(size_t)(k0 + kr) * 64 + cg * 4]);
        *reinterpret_cast<float4*>(&Xs[kr][cg * 4]) = val;
      }
    }
    __syncthreads();

#pragma unroll
    for (int kk = 0; kk < 64; kk += 4) {
      float a_[4][4], x_[4][4];
#pragma unroll
      for (int i = 0; i < 4; ++i) {
        float4 t = *reinterpret_cast<float4*>(&As[ty * 4 + i][kk]);
        a_[i][0] = t.x; a_[i][1] = t.y; a_[i][2] = t.z; a_[i][3] = t.w;
      }
#pragma unroll
      for (int s = 0; s < 4; ++s) {
        float4 t = *reinterpret_cast<float4*>(&Xs[kk + s][tx * 4]);
        x_[s][0] = t.x; x_[s][1] = t.y; x_[s][2] = t.z; x_[s][3] = t.w;
      }
#pragma unroll
      for (int i = 0; i < 4; ++i)
#pragma unroll
        for (int j = 0; j < 4; ++j) {
          float r = acc[i][j];
          r = fmaf(a_[i][0], x_[0][j], r);
          r = fmaf(a_[i][1], x_[1][j], r);
          r = fmaf(a_[i][2], x_[2][j], r);
          r = fmaf(a_[i][3], x_[3][j], r);
          acc[i][j] = r;
        }
    }
    __syncthreads();
  }

#pragma unroll
  for (int i = 0; i < 4; ++i) {
    int gr = row0 + ty * 4 + i;
    if (gr >= M) continue;
#pragma unroll
    for (int j = 0; j < 4; ++j) {
      int gc = tx * 4 + j;
      float v = acc[i][j];
      if (EPI == 0)      atomicAdd(&C[(size_t)gr * 64 + gc], v);
      else if (EPI == 1) C[(size_t)gr * 64 + gc] = v;
      else               C[(size_t)gr * 64 + gc] = fmaxf(v + bias[gc], 0.f);
    }
  }
}

// o = relu(a) + relu(b) + c, elementwise
__global__ __launch_bounds__(256) void ew3relu(const float* __restrict__ a,
                                               const float* __restrict__ b,
                                               const float* __restrict__ c,
                                               float* __restrict__ o, int n)
{
  int i = blockIdx.x * 256 + threadIdx.x;
  if (i < n) o[i] = fmaxf(a[i], 0.f) + fmaxf(b[i], 0.f) + c[i];
}

// Flash attention: 8 heads, dh=8, n=3072. grid (96, 8), block 256 = 32 queries x 8 parts.
__global__ __launch_bounds__(256) void attn_kernel(const float* __restrict__ q,
                                                   const float* __restrict__ k,
                                                   const float* __restrict__ v,
                                                   float* __restrict__ o)
{
  __shared__ float Ks[256][8];
  __shared__ float Vs[256][8];
  const int h = blockIdx.y;
  const int tid = threadIdx.x;
  const int qi = tid >> 3, p = tid & 7;
  const int n = blockIdx.x * 32 + qi;

  float qr[8];
#pragma unroll
  for (int j = 0; j < 8; ++j) qr[j] = q[n * 64 + h * 8 + j] * 0.3535533905932738f;

  float mx = -1e30f, sum = 0.f, acc[8] = {};

  for (int m0 = 0; m0 < I_N; m0 += 256) {
    __syncthreads();
    {
      const float* kp = &k[(size_t)(m0 + tid) * 64 + h * 8];
      const float* vp = &v[(size_t)(m0 + tid) * 64 + h * 8];
      float4 a0 = *reinterpret_cast<const float4*>(kp);
      float4 a1 = *reinterpret_cast<const float4*>(kp + 4);
      float4 b0 = *reinterpret_cast<const float4*>(vp);
      float4 b1 = *reinterpret_cast<const float4*>(vp + 4);
      *reinterpret_cast<float4*>(&Ks[tid][0]) = a0;
      *reinterpret_cast<float4*>(&Ks[tid][4]) = a1;
      *reinterpret_cast<float4*>(&Vs[tid][0]) = b0;
      *reinterpret_cast<float4*>(&Vs[tid][4]) = b1;
    }
    __syncthreads();
    for (int mm = p; mm < 256; mm += 8) {
      float s = 0.f;
#pragma unroll
      for (int j = 0; j < 8; ++j) s = fmaf(qr[j], Ks[mm][j], s);
      float nm = fmaxf(mx, s);
      float corr = __expf(mx - nm);
      float w = __expf(s - nm);
      sum = sum * corr + w;
#pragma unroll
      for (int j = 0; j < 8; ++j) acc[j] = acc[j] * corr + w * Vs[mm][j];
      mx = nm;
    }
  }
  // merge the 8 partials (lanes differing in bits 0..2 share a query)
#pragma unroll
  for (int d = 1; d < 8; d <<= 1) {
    float omx = __shfl_xor(mx, d, 64);
    float osum = __shfl_xor(sum, d, 64);
    float nm = fmaxf(mx, omx);
    float c1 = __expf(mx - nm), c2 = __expf(omx - nm);
    float nsum = sum * c1 + osum * c2;
#pragma unroll
    for (int j = 0; j < 8; ++j) {
      float oa = __shfl_xor(acc[j], d, 64);
      acc[j] = acc[j] * c1 + oa * c2;
    }
    mx = nm; sum = nsum;
  }
  if (p == 0) {
    float inv = 1.f / sum;
#pragma unroll
    for (int j = 0; j < 8; ++j) o[n * 64 + h * 8 + j] = acc[j] * inv;
  }
}

// Per bundle row r (3000): bundles_f = relu(P)+bfeat -> fub0 rows 6000+, b1 = l2norm(relu(P))
__global__ __launch_bounds__(256) void bundle_row(const float* __restrict__ P,
                                                  const float* __restrict__ bfeat,
                                                  float* __restrict__ fub0,
                                                  float* __restrict__ b1)
{
  int r = blockIdx.x * 4 + (threadIdx.x >> 6);
  int c = threadIdx.x & 63;
  float pv = fmaxf(P[(size_t)r * 64 + c], 0.f);
  fub0[(size_t)(6000 + r) * 64 + c] = pv + bfeat[(size_t)r * 64 + c];
  float n2 = wsum64(pv * pv);
  b1[(size_t)r * 64 + c] = pv / fmaxf(sqrtf(n2), 1e-12f);
}

// Per row r (9000): att2-fuse + l2norm(feat_ub) + assemble all_ub[r][0..191]
__global__ __launch_bounds__(256) void fuse_ub(const float* __restrict__ fub0,
                                               const float* __restrict__ b1,
                                               const float* __restrict__ f_ub,
                                               const float* __restrict__ w,
                                               float* __restrict__ all_ub)
{
  int r = blockIdx.x * 4 + (threadIdx.x >> 6);
  int c = threadIdx.x & 63;
  float x0 = fub0[(size_t)r * 64 + c];
  float x1 = (r < U_N) ? x0 : b1[(size_t)(r - U_N) * 64 + c];
  float wv = w[c];
  float s0 = wsum64(x0 * wv);
  float s1 = wsum64(x1 * wv);
  float mxs = fmaxf(s0, s1);
  float e0 = __expf(s0 - mxs), e1 = __expf(s1 - mxs);
  float fused = (e0 * x0 + e1 * x1) / (e0 + e1);
  float fu = f_ub[(size_t)r * 64 + c];
  float n2 = wsum64(fu * fu + fused * fused);
  float inv = 1.f / fmaxf(sqrtf(n2), 1e-12f);
  float* row = &all_ub[(size_t)r * 192];
  row[c]        = x0;
  row[64 + c]   = fu * inv;
  row[128 + c]  = fused * inv;
}

// Final gather + 576->8 relu MLP -> 1. One wave per batch row. grid 1024, block 256.
__global__ __launch_bounds__(256) void final_mlp(const float* __restrict__ all_ub,
                                                 const int* __restrict__ users,
                                                 const int* __restrict__ bundles,
                                                 const float* __restrict__ p1W,
                                                 const float* __restrict__ p1b,
                                                 const float* __restrict__ p2W,
                                                 const float* __restrict__ p2b,
                                                 float* __restrict__ out)
{
  __shared__ float W[576 * 8];
  for (int i = threadIdx.x; i < 576 * 8; i += 256) W[i] = p1W[i];
  __syncthreads();
  int j = blockIdx.x * 4 + (threadIdx.x >> 6);
  int lane = threadIdx.x & 63;
  const float* ue = &all_ub[(size_t)users[j] * 192];
  const float* be = &all_ub[(size_t)(U_N + bundles[j]) * 192];
  float hacc[8] = {};
#pragma unroll
  for (int db = 0; db < 9; ++db) {
    int d = db * 64 + lane;
    float ne;
    if (d < 192)      ne = ue[d] * be[d];
    else if (d < 384) ne = be[d - 192];
    else              ne = ue[d - 384];
#pragma unroll
    for (int h = 0; h < 8; ++h) hacc[h] = fmaf(ne, W[d * 8 + h], hacc[h]);
  }
#pragma unroll
  for (int d = 1; d < 64; d <<= 1)
#pragma unroll
    for (int h = 0; h < 8; ++h) hacc[h] += __shfl_xor(hacc[h], d, 64);
  if (lane == 0) {
    float o = p2b[0];
#pragma unroll
    for (int h = 0; h < 8; ++h) o += fmaxf(hacc[h] + p1b[h], 0.f) * p2W[h];
    out[j] = o;
  }
}

extern "C" void kernel_launch(void* const* d_in, const int* in_sizes, int n_in,
                              void* d_out, int out_size, void* d_ws, size_t ws_size,
                              hipStream_t stream)
{
  const float* ufeat   = (const float*)d_in[0];
  const float* ifeat   = (const float*)d_in[1];
  const float* bfeat   = (const float*)d_in[2];
  const float* Wq      = (const float*)d_in[3];
  const float* Wk      = (const float*)d_in[4];
  const float* Wv      = (const float*)d_in[5];
  const float* Wo      = (const float*)d_in[6];
  const float* W_ub    = (const float*)d_in[7];
  const float* b_ub    = (const float*)d_in[8];
  // d_in[9] W_ui, d_in[10] b_ui: dead in reference
  const float* att_b_w = (const float*)d_in[11];
  // d_in[12] att_i_w: dead
  const float* p1W     = (const float*)d_in[13];
  const float* p1b     = (const float*)d_in[14];
  const float* p2W     = (const float*)d_in[15];
  const float* p2b     = (const float*)d_in[16];
  const float* A_i     = (const float*)d_in[17];
  const float* B_i     = (const float*)d_in[18];
  const float* bi_avg  = (const float*)d_in[19];
  const float* ui_avg  = (const float*)d_in[20];
  const float* ub_avg  = (const float*)d_in[21];
  // d_in[22] ib_avg: dead
  const float* ubg     = (const float*)d_in[23];
  // d_in[24] ui_graph: dead
  const int* users     = (const int*)d_in[25];
  const int* bundles   = (const int*)d_in[26];

  float* ws = (float*)d_ws;
  float* t1     = ws;  ws += I_N * 64;        // 3072x64
  float* t2     = ws;  ws += I_N * 64;
  float* items0 = ws;  ws += I_N * 64;
  float* qb     = ws;  ws += I_N * 64;
  float* kb     = ws;  ws += I_N * 64;
  float* vb     = ws;  ws += I_N * 64;
  float* attnb  = ws;  ws += I_N * 64;
  float* items  = ws;  ws += I_N * 64;
  float* P      = ws;  ws += B_N * 64;        // 3000x64
  float* b1     = ws;  ws += B_N * 64;
  float* fub0   = ws;  ws += 9000 * 64;       // users_f rows 0..5999, bundles_f 6000..8999
  float* t3     = ws;  ws += U_N * 64;
  float* t4     = ws;  ws += U_N * 64;
  float* tmp    = ws;  ws += 9000 * 64;
  float* f_ub   = ws;  ws += 9000 * 64;
  float* all_ub = ws;  ws += 9000 * 192;

  // ---- items0 = relu(A_i@itf) + relu(B_i@itf) + itf ----
  hipMemsetAsync(t1, 0, (size_t)I_N * 64 * 4, stream);
  hipMemsetAsync(t2, 0, (size_t)I_N * 64 * 4, stream);
  gemm64<0><<<dim3(48, 6), 256, 0, stream>>>(A_i, ifeat, t1, nullptr, I_N, I_N, 512);
  gemm64<0><<<dim3(48, 6), 256, 0, stream>>>(B_i, ifeat, t2, nullptr, I_N, I_N, 512);
  ew3relu<<<768, 256, 0, stream>>>(t1, t2, ifeat, items0, I_N * 64);

  // ---- multi-head attention ----
  gemm64<1><<<dim3(48, 1), 256, 0, stream>>>(items0, Wq, qb, nullptr, I_N, 64, 64);
  gemm64<1><<<dim3(48, 1), 256, 0, stream>>>(items0, Wk, kb, nullptr, I_N, 64, 64);
  gemm64<1><<<dim3(48, 1), 256, 0, stream>>>(items0, Wv, vb, nullptr, I_N, 64, 64);
  attn_kernel<<<dim3(96, 8), 256, 0, stream>>>(qb, kb, vb, attnb);
  gemm64<1><<<dim3(48, 1), 256, 0, stream>>>(attnb, Wo, items, nullptr, I_N, 64, 64);

  // ---- bundles_f + b1 ----
  hipMemsetAsync(P, 0, (size_t)B_N * 64 * 4, stream);
  gemm64<0><<<dim3(47, 6), 256, 0, stream>>>(bi_avg, items, P, nullptr, B_N, I_N, 512);
  bundle_row<<<750, 256, 0, stream>>>(P, bfeat, fub0, b1);

  // ---- users_f ----
  hipMemsetAsync(t3, 0, (size_t)U_N * 64 * 4, stream);
  hipMemsetAsync(t4, 0, (size_t)U_N * 64 * 4, stream);
  gemm64<0><<<dim3(94, 3), 256, 0, stream>>>(ui_avg, items, t3, nullptr, U_N, I_N, 1024);
  gemm64<0><<<dim3(94, 3), 256, 0, stream>>>(ub_avg, fub0 + (size_t)U_N * 64, t4, nullptr, U_N, B_N, 1024);
  ew3relu<<<1500, 256, 0, stream>>>(t3, t4, ufeat, fub0, U_N * 64);

  // ---- f_ub = relu((ub_graph @ f_ub0) @ W_ub + b_ub) ----
  hipMemsetAsync(tmp, 0, (size_t)9000 * 64 * 4, stream);
  gemm64<0><<<dim3(141, 4), 256, 0, stream>>>(ubg, fub0, tmp, nullptr, 9000, 9000, 2304);
  gemm64<2><<<dim3(141, 1), 256, 0, stream>>>(tmp, W_ub, f_ub, b_ub, 9000, 64, 64);

  // ---- att2 fuse + l2norm + all_ub assembly ----
  fuse_ub<<<2250, 256, 0, stream>>>(fub0, b1, f_ub, att_b_w, all_ub);

  // ---- gather + final MLP ----
  final_mlp<<<1024, 256, 0, stream>>>(all_ub, users, bundles, p1W, p1b, p2W, p2b,
                                      (float*)d_out);
}

// Round 2
// 1053.676 us; speedup vs baseline: 1.2943x; 1.2943x over previous
//
#include <hip/hip_runtime.h>
#include <math.h>

#define U_N 6000
#define I_N 3072
#define B_N 3000

typedef short short8 __attribute__((ext_vector_type(8)));
typedef float f32x4 __attribute__((ext_vector_type(4)));

__device__ __forceinline__ float wsum64(float v) {
#pragma unroll
  for (int d = 1; d < 64; d <<= 1) v += __shfl_xor(v, d, 64);
  return v;
}

// truncation-based bf16 hi/lo split: v = hi + lo + O(2^-14 |v|)
__device__ __forceinline__ void cvt_split(float v, short& h, short& l) {
  unsigned u = __float_as_uint(v);
  h = (short)(u >> 16);
  float lo = v - __uint_as_float(u & 0xFFFF0000u);
  l = (short)(__float_as_uint(lo) >> 16);
}

// Pack X[K x 64] f32 -> Xh/Xl, layout [kg][c][8] bf16 (16B per (kg,c)), kg = k/8,
// zero-padded to Kpad = ceil(K/32)*32. rows = Kpad/8.
__global__ __launch_bounds__(256) void pack_x(const float* __restrict__ X,
                                              short* __restrict__ Xh,
                                              short* __restrict__ Xl,
                                              int K, int rows)
{
  int idx = blockIdx.x * 256 + threadIdx.x;
  if (idx >= rows * 64) return;
  int kg = idx >> 6, c = idx & 63;
  short8 hv, lv;
#pragma unroll
  for (int j = 0; j < 8; ++j) {
    int k = kg * 8 + j;
    float v = (k < K) ? X[(size_t)k * 64 + c] : 0.f;
    short h, l;
    cvt_split(v, h, l);
    hv[j] = h; lv[j] = l;
  }
  ((short8*)Xh)[idx] = hv;
  ((short8*)Xl)[idx] = lv;
}

// Pack the five 64x64 weight matrices (Wq,Wk,Wv,Wo,W_ub). 512 short8 per matrix.
__global__ __launch_bounds__(512) void pack_w5(const float* __restrict__ W0,
                                               const float* __restrict__ W1,
                                               const float* __restrict__ W2,
                                               const float* __restrict__ W3,
                                               const float* __restrict__ W4,
                                               short* __restrict__ H,
                                               short* __restrict__ L)
{
  int m = blockIdx.x;
  const float* W = (m == 0) ? W0 : (m == 1) ? W1 : (m == 2) ? W2 : (m == 3) ? W3 : W4;
  int kg = threadIdx.x >> 6, c = threadIdx.x & 63;
  short8 hv, lv;
#pragma unroll
  for (int j = 0; j < 8; ++j) {
    float v = W[(kg * 8 + j) * 64 + c];
    short h, l;
    cvt_split(v, h, l);
    hv[j] = h; lv[j] = l;
  }
  ((short8*)H)[m * 512 + kg * 64 + c] = hv;
  ((short8*)L)[m * 512 + kg * 64 + c] = lv;
}

// C[M x 64] (+)= A[M x K] @ X[K x 64]; A f32 row-major streamed from HBM,
// X pre-packed bf16 hi/lo. Split-precision: 3 MFMA products per fragment pair.
// Block = 128 threads = 2 waves; wave handles 32 rows. grid = (ceil(M/64), splitk).
// EPI 0: atomicAdd into pre-zeroed C; 1: direct store; 2: relu(acc + bias[col]).
// kchunk must be a multiple of 32.
template <int EPI>
__global__ __launch_bounds__(128, 3) void gemm_mfma(
    const float* __restrict__ A, const short* __restrict__ Xh,
    const short* __restrict__ Xl, float* __restrict__ C,
    const float* __restrict__ bias, int M, int K, int kchunk)
{
  const int lane = threadIdx.x & 63;
  const int wave = threadIdx.x >> 6;
  const int r16 = lane & 15;     // row within A-frag / col within B-frag
  const int kq = lane >> 4;      // k-quarter (0..3)
  const int row0 = blockIdx.x * 64 + wave * 32;
  const int ks = blockIdx.y * kchunk;
  if (ks >= K) return;
  const int ke = min(K, ks + kchunk);

  f32x4 acc[2][4];
#pragma unroll
  for (int i = 0; i < 2; ++i)
#pragma unroll
    for (int j = 0; j < 4; ++j)
#pragma unroll
      for (int e = 0; e < 4; ++e) acc[i][j][e] = 0.f;

  const int r0 = row0 + r16;
  const int r1 = r0 + 16;
  const bool v0 = r0 < M, v1 = r1 < M;
  const float* pA0 = A + (size_t)r0 * K;
  const float* pA1 = A + (size_t)r1 * K;
  const short8* BH = (const short8*)Xh;
  const short8* BL = (const short8*)Xl;
  const f32x4 z4 = {0.f, 0.f, 0.f, 0.f};

  for (int k0 = ks; k0 < ke; k0 += 32) {
    const int kk = k0 + kq * 8;   // this lane's 8 k's
    f32x4 a0lo, a0hi, a1lo, a1hi;
    if (k0 + 32 <= ke) {
      a0lo = v0 ? *(const f32x4*)(pA0 + kk)     : z4;
      a0hi = v0 ? *(const f32x4*)(pA0 + kk + 4) : z4;
      a1lo = v1 ? *(const f32x4*)(pA1 + kk)     : z4;
      a1hi = v1 ? *(const f32x4*)(pA1 + kk + 4) : z4;
    } else {  // ragged K tail (only when ke == K, K % 32 != 0)
#pragma unroll
      for (int j = 0; j < 4; ++j) {
        a0lo[j] = (v0 && kk + j < ke)     ? pA0[kk + j]     : 0.f;
        a0hi[j] = (v0 && kk + 4 + j < ke) ? pA0[kk + 4 + j] : 0.f;
        a1lo[j] = (v1 && kk + j < ke)     ? pA1[kk + j]     : 0.f;
        a1hi[j] = (v1 && kk + 4 + j < ke) ? pA1[kk + 4 + j] : 0.f;
      }
    }
    short8 ah0, al0, ah1, al1;
#pragma unroll
    for (int j = 0; j < 4; ++j) {
      short h, l;
      cvt_split(a0lo[j], h, l); ah0[j] = h;     al0[j] = l;
      cvt_split(a0hi[j], h, l); ah0[j + 4] = h; al0[j + 4] = l;
      cvt_split(a1lo[j], h, l); ah1[j] = h;     al1[j] = l;
      cvt_split(a1hi[j], h, l); ah1[j + 4] = h; al1[j + 4] = l;
    }
    const size_t xrow = ((size_t)(k0 >> 3) + kq) * 64;
    short8 bh[4], bl[4];
#pragma unroll
    for (int cg = 0; cg < 4; ++cg) {
      bh[cg] = BH[xrow + cg * 16 + r16];
      bl[cg] = BL[xrow + cg * 16 + r16];
    }
#pragma unroll
    for (int cg = 0; cg < 4; ++cg) {
      acc[0][cg] = __builtin_amdgcn_mfma_f32_16x16x32_bf16(ah0, bh[cg], acc[0][cg], 0, 0, 0);
      acc[0][cg] = __builtin_amdgcn_mfma_f32_16x16x32_bf16(ah0, bl[cg], acc[0][cg], 0, 0, 0);
      acc[0][cg] = __builtin_amdgcn_mfma_f32_16x16x32_bf16(al0, bh[cg], acc[0][cg], 0, 0, 0);
      acc[1][cg] = __builtin_amdgcn_mfma_f32_16x16x32_bf16(ah1, bh[cg], acc[1][cg], 0, 0, 0);
      acc[1][cg] = __builtin_amdgcn_mfma_f32_16x16x32_bf16(ah1, bl[cg], acc[1][cg], 0, 0, 0);
      acc[1][cg] = __builtin_amdgcn_mfma_f32_16x16x32_bf16(al1, bh[cg], acc[1][cg], 0, 0, 0);
    }
  }

  // epilogue: C/D frag mapping col = lane&15, row = (lane>>4)*4 + i
#pragma unroll
  for (int rg = 0; rg < 2; ++rg) {
#pragma unroll
    for (int i = 0; i < 4; ++i) {
      int row = row0 + rg * 16 + kq * 4 + i;
      if (row < M) {
#pragma unroll
        for (int cg = 0; cg < 4; ++cg) {
          int col = cg * 16 + r16;
          float v = acc[rg][cg][i];
          if (EPI == 0)      atomicAdd(&C[(size_t)row * 64 + col], v);
          else if (EPI == 1) C[(size_t)row * 64 + col] = v;
          else               C[(size_t)row * 64 + col] = fmaxf(v + bias[col], 0.f);
        }
      }
    }
  }
}

// o = relu(a) + relu(b) + c, elementwise
__global__ __launch_bounds__(256) void ew3relu(const float* __restrict__ a,
                                               const float* __restrict__ b,
                                               const float* __restrict__ c,
                                               float* __restrict__ o, int n)
{
  int i = blockIdx.x * 256 + threadIdx.x;
  if (i < n) o[i] = fmaxf(a[i], 0.f) + fmaxf(b[i], 0.f) + c[i];
}

// Flash attention: 8 heads, dh=8, n=3072. grid (96, 8), block 256 = 32 queries x 8 parts.
__global__ __launch_bounds__(256) void attn_kernel(const float* __restrict__ q,
                                                   const float* __restrict__ k,
                                                   const float* __restrict__ v,
                                                   float* __restrict__ o)
{
  __shared__ float Ks[256][8];
  __shared__ float Vs[256][8];
  const int h = blockIdx.y;
  const int tid = threadIdx.x;
  const int qi = tid >> 3, p = tid & 7;
  const int n = blockIdx.x * 32 + qi;

  float qr[8];
#pragma unroll
  for (int j = 0; j < 8; ++j) qr[j] = q[n * 64 + h * 8 + j] * 0.3535533905932738f;

  float mx = -1e30f, sum = 0.f, acc[8] = {};

  for (int m0 = 0; m0 < I_N; m0 += 256) {
    __syncthreads();
    {
      const float* kp = &k[(size_t)(m0 + tid) * 64 + h * 8];
      const float* vp = &v[(size_t)(m0 + tid) * 64 + h * 8];
      float4 a0 = *reinterpret_cast<const float4*>(kp);
      float4 a1 = *reinterpret_cast<const float4*>(kp + 4);
      float4 b0 = *reinterpret_cast<const float4*>(vp);
      float4 b1 = *reinterpret_cast<const float4*>(vp + 4);
      *reinterpret_cast<float4*>(&Ks[tid][0]) = a0;
      *reinterpret_cast<float4*>(&Ks[tid][4]) = a1;
      *reinterpret_cast<float4*>(&Vs[tid][0]) = b0;
      *reinterpret_cast<float4*>(&Vs[tid][4]) = b1;
    }
    __syncthreads();
    for (int mm = p; mm < 256; mm += 8) {
      float s = 0.f;
#pragma unroll
      for (int j = 0; j < 8; ++j) s = fmaf(qr[j], Ks[mm][j], s);
      float nm = fmaxf(mx, s);
      float corr = __expf(mx - nm);
      float w = __expf(s - nm);
      sum = sum * corr + w;
#pragma unroll
      for (int j = 0; j < 8; ++j) acc[j] = acc[j] * corr + w * Vs[mm][j];
      mx = nm;
    }
  }
#pragma unroll
  for (int d = 1; d < 8; d <<= 1) {
    float omx = __shfl_xor(mx, d, 64);
    float osum = __shfl_xor(sum, d, 64);
    float nm = fmaxf(mx, omx);
    float c1 = __expf(mx - nm), c2 = __expf(omx - nm);
    float nsum = sum * c1 + osum * c2;
#pragma unroll
    for (int j = 0; j < 8; ++j) {
      float oa = __shfl_xor(acc[j], d, 64);
      acc[j] = acc[j] * c1 + oa * c2;
    }
    mx = nm; sum = nsum;
  }
  if (p == 0) {
    float inv = 1.f / sum;
#pragma unroll
    for (int j = 0; j < 8; ++j) o[n * 64 + h * 8 + j] = acc[j] * inv;
  }
}

// Per bundle row r: bundles_f = relu(P)+bfeat -> fub0 rows 6000+, b1 = l2norm(relu(P))
__global__ __launch_bounds__(256) void bundle_row(const float* __restrict__ P,
                                                  const float* __restrict__ bfeat,
                                                  float* __restrict__ fub0,
                                                  float* __restrict__ b1)
{
  int r = blockIdx.x * 4 + (threadIdx.x >> 6);
  int c = threadIdx.x & 63;
  float pv = fmaxf(P[(size_t)r * 64 + c], 0.f);
  fub0[(size_t)(6000 + r) * 64 + c] = pv + bfeat[(size_t)r * 64 + c];
  float n2 = wsum64(pv * pv);
  b1[(size_t)r * 64 + c] = pv / fmaxf(sqrtf(n2), 1e-12f);
}

// Per row r (9000): att2-fuse + l2norm(feat_ub) + assemble all_ub[r][0..191]
__global__ __launch_bounds__(256) void fuse_ub(const float* __restrict__ fub0,
                                               const float* __restrict__ b1,
                                               const float* __restrict__ f_ub,
                                               const float* __restrict__ w,
                                               float* __restrict__ all_ub)
{
  int r = blockIdx.x * 4 + (threadIdx.x >> 6);
  int c = threadIdx.x & 63;
  float x0 = fub0[(size_t)r * 64 + c];
  float x1 = (r < U_N) ? x0 : b1[(size_t)(r - U_N) * 64 + c];
  float wv = w[c];
  float s0 = wsum64(x0 * wv);
  float s1 = wsum64(x1 * wv);
  float mxs = fmaxf(s0, s1);
  float e0 = __expf(s0 - mxs), e1 = __expf(s1 - mxs);
  float fused = (e0 * x0 + e1 * x1) / (e0 + e1);
  float fu = f_ub[(size_t)r * 64 + c];
  float n2 = wsum64(fu * fu + fused * fused);
  float inv = 1.f / fmaxf(sqrtf(n2), 1e-12f);
  float* row = &all_ub[(size_t)r * 192];
  row[c]       = x0;
  row[64 + c]  = fu * inv;
  row[128 + c] = fused * inv;
}

// Final gather + 576->8 relu MLP -> 1. One wave per batch row. grid 1024, block 256.
__global__ __launch_bounds__(256) void final_mlp(const float* __restrict__ all_ub,
                                                 const int* __restrict__ users,
                                                 const int* __restrict__ bundles,
                                                 const float* __restrict__ p1W,
                                                 const float* __restrict__ p1b,
                                                 const float* __restrict__ p2W,
                                                 const float* __restrict__ p2b,
                                                 float* __restrict__ out)
{
  __shared__ float W[576 * 8];
  for (int i = threadIdx.x; i < 576 * 8; i += 256) W[i] = p1W[i];
  __syncthreads();
  int j = blockIdx.x * 4 + (threadIdx.x >> 6);
  int lane = threadIdx.x & 63;
  const float* ue = &all_ub[(size_t)users[j] * 192];
  const float* be = &all_ub[(size_t)(U_N + bundles[j]) * 192];
  float hacc[8] = {};
#pragma unroll
  for (int db = 0; db < 9; ++db) {
    int d = db * 64 + lane;
    float ne;
    if (d < 192)      ne = ue[d] * be[d];
    else if (d < 384) ne = be[d - 192];
    else              ne = ue[d - 384];
#pragma unroll
    for (int h = 0; h < 8; ++h) hacc[h] = fmaf(ne, W[d * 8 + h], hacc[h]);
  }
#pragma unroll
  for (int d = 1; d < 64; d <<= 1)
#pragma unroll
    for (int h = 0; h < 8; ++h) hacc[h] += __shfl_xor(hacc[h], d, 64);
  if (lane == 0) {
    float o = p2b[0];
#pragma unroll
    for (int h = 0; h < 8; ++h) o += fmaxf(hacc[h] + p1b[h], 0.f) * p2W[h];
    out[j] = o;
  }
}

extern "C" void kernel_launch(void* const* d_in, const int* in_sizes, int n_in,
                              void* d_out, int out_size, void* d_ws, size_t ws_size,
                              hipStream_t stream)
{
  const float* ufeat   = (const float*)d_in[0];
  const float* ifeat   = (const float*)d_in[1];
  const float* bfeat   = (const float*)d_in[2];
  const float* Wq      = (const float*)d_in[3];
  const float* Wk      = (const float*)d_in[4];
  const float* Wv      = (const float*)d_in[5];
  const float* Wo      = (const float*)d_in[6];
  const float* W_ub    = (const float*)d_in[7];
  const float* b_ub    = (const float*)d_in[8];
  const float* att_b_w = (const float*)d_in[11];
  const float* p1W     = (const float*)d_in[13];
  const float* p1b     = (const float*)d_in[14];
  const float* p2W     = (const float*)d_in[15];
  const float* p2b     = (const float*)d_in[16];
  const float* A_i     = (const float*)d_in[17];
  const float* B_i     = (const float*)d_in[18];
  const float* bi_avg  = (const float*)d_in[19];
  const float* ui_avg  = (const float*)d_in[20];
  const float* ub_avg  = (const float*)d_in[21];
  const float* ubg     = (const float*)d_in[23];
  const int* users     = (const int*)d_in[25];
  const int* bundles   = (const int*)d_in[26];

  float* ws = (float*)d_ws;
  float* t1     = ws;  ws += I_N * 64;
  float* t2     = ws;  ws += I_N * 64;
  float* items0 = ws;  ws += I_N * 64;
  float* qb     = ws;  ws += I_N * 64;
  float* kb     = ws;  ws += I_N * 64;
  float* vb     = ws;  ws += I_N * 64;
  float* attnb  = ws;  ws += I_N * 64;
  float* items  = ws;  ws += I_N * 64;
  float* P      = ws;  ws += B_N * 64;
  float* b1     = ws;  ws += B_N * 64;
  float* fub0   = ws;  ws += 9000 * 64;
  float* t3     = ws;  ws += U_N * 64;
  float* t4     = ws;  ws += U_N * 64;
  float* tmp    = ws;  ws += 9000 * 64;
  float* f_ub   = ws;  ws += 9000 * 64;
  float* all_ub = ws;  ws += 9000 * 192;
  // packed X buffers (short = half a float slot). sizes in float units = Kpad*64/2
  short* if_h  = (short*)ws; ws += 98304;   // K=3072
  short* if_l  = (short*)ws; ws += 98304;
  short* it_h  = (short*)ws; ws += 98304;   // K=3072
  short* it_l  = (short*)ws; ws += 98304;
  short* bf_h  = (short*)ws; ws += 96256;   // K=3000 -> Kpad 3008
  short* bf_l  = (short*)ws; ws += 96256;
  short* f0_h  = (short*)ws; ws += 288768;  // K=9000 -> Kpad 9024
  short* f0_l  = (short*)ws; ws += 288768;
  short* w5_h  = (short*)ws; ws += 10240;   // 5 x 64x64
  short* w5_l  = (short*)ws; ws += 10240;

  auto rowsOf = [](int K) { return ((K + 31) / 32) * 4; };

  // ---- packs available immediately ----
  pack_x<<<(rowsOf(3072) * 64) / 256, 256, 0, stream>>>(ifeat, if_h, if_l, 3072, rowsOf(3072));
  pack_w5<<<5, 512, 0, stream>>>(Wq, Wk, Wv, Wo, W_ub, w5_h, w5_l);

  // ---- items0 = relu(A_i@itf) + relu(B_i@itf) + itf ----
  hipMemsetAsync(t1, 0, (size_t)I_N * 64 * 4, stream);
  hipMemsetAsync(t2, 0, (size_t)I_N * 64 * 4, stream);
  gemm_mfma<0><<<dim3(48, 16), 128, 0, stream>>>(A_i, if_h, if_l, t1, nullptr, I_N, I_N, 192);
  gemm_mfma<0><<<dim3(48, 16), 128, 0, stream>>>(B_i, if_h, if_l, t2, nullptr, I_N, I_N, 192);
  ew3relu<<<768, 256, 0, stream>>>(t1, t2, ifeat, items0, I_N * 64);

  // ---- multi-head attention ----
  gemm_mfma<1><<<dim3(48, 1), 128, 0, stream>>>(items0, w5_h + 0 * 4096, w5_l + 0 * 4096, qb, nullptr, I_N, 64, 64);
  gemm_mfma<1><<<dim3(48, 1), 128, 0, stream>>>(items0, w5_h + 1 * 4096, w5_l + 1 * 4096, kb, nullptr, I_N, 64, 64);
  gemm_mfma<1><<<dim3(48, 1), 128, 0, stream>>>(items0, w5_h + 2 * 4096, w5_l + 2 * 4096, vb, nullptr, I_N, 64, 64);
  attn_kernel<<<dim3(96, 8), 256, 0, stream>>>(qb, kb, vb, attnb);
  gemm_mfma<1><<<dim3(48, 1), 128, 0, stream>>>(attnb, w5_h + 3 * 4096, w5_l + 3 * 4096, items, nullptr, I_N, 64, 64);
  pack_x<<<(rowsOf(3072) * 64) / 256, 256, 0, stream>>>(items, it_h, it_l, 3072, rowsOf(3072));

  // ---- bundles_f + b1 ----
  hipMemsetAsync(P, 0, (size_t)B_N * 64 * 4, stream);
  gemm_mfma<0><<<dim3(47, 16), 128, 0, stream>>>(bi_avg, it_h, it_l, P, nullptr, B_N, I_N, 192);
  bundle_row<<<750, 256, 0, stream>>>(P, bfeat, fub0, b1);
  pack_x<<<(rowsOf(3000) * 64) / 256, 256, 0, stream>>>(fub0 + (size_t)U_N * 64, bf_h, bf_l, 3000, rowsOf(3000));

  // ---- users_f ----
  hipMemsetAsync(t3, 0, (size_t)U_N * 64 * 4, stream);
  hipMemsetAsync(t4, 0, (size_t)U_N * 64 * 4, stream);
  gemm_mfma<0><<<dim3(94, 8), 128, 0, stream>>>(ui_avg, it_h, it_l, t3, nullptr, U_N, I_N, 384);
  gemm_mfma<0><<<dim3(94, 8), 128, 0, stream>>>(ub_avg, bf_h, bf_l, t4, nullptr, U_N, B_N, 384);
  ew3relu<<<1500, 256, 0, stream>>>(t3, t4, ufeat, fub0, U_N * 64);
  pack_x<<<(rowsOf(9000) * 64) / 256, 256, 0, stream>>>(fub0, f0_h, f0_l, 9000, rowsOf(9000));

  // ---- f_ub = relu((ub_graph @ f_ub0) @ W_ub + b_ub) ----
  hipMemsetAsync(tmp, 0, (size_t)9000 * 64 * 4, stream);
  gemm_mfma<0><<<dim3(141, 16), 128, 0, stream>>>(ubg, f0_h, f0_l, tmp, nullptr, 9000, 9000, 576);
  gemm_mfma<2><<<dim3(141, 1), 128, 0, stream>>>(tmp, w5_h + 4 * 4096, w5_l + 4 * 4096, f_ub, b_ub, 9000, 64, 64);

  // ---- att2 fuse + l2norm + all_ub assembly ----
  fuse_ub<<<2250, 256, 0, stream>>>(fub0, b1, f_ub, att_b_w, all_ub);

  // ---- gather + final MLP ----
  final_mlp<<<1024, 256, 0, stream>>>(all_ub, users, bundles, p1W, p1b, p2W, p2b,
                                      (float*)d_out);
}